// Round 7
// baseline (232.874 us; speedup 1.0000x reference)
//
#include <hip/hip_runtime.h>

// N=4096, A=512, C=100 (derived at launch).
// Outputs flat: [loss(1), new_cov(C*A*A), new_ave(C*A), new_amount(C)]
//
// 3 dispatches:
//   prep  : 1 block — histogram, scan, per-class scalars, counting-sort, zero loss.
//   ave   : C blocks — per-class mean + new_ave.
//   cov   : grid (A/TM, A/TM, C+LZ). z<C: 128x128 cov tile, fp32 8x8/thread,
//           float4 + nontemporal stores, cov_in read skipped when w==1.
//           z>=C: LZ*16 blocks compute CE loss (balanced, overlaps cov drain).

#define TM 128
#define KC 32      // members per k-chunk (nc ~ 41 -> 2 chunks, 4 barriers total)
#define LSTR 132   // padded LDS row stride (floats)
#define LZ 16      // extra z-slices for loss blocks

typedef float nf4 __attribute__((ext_vector_type(4)));   // native vector for nontemporal builtins

// ---------------- prep ----------------
__global__ __launch_bounds__(1024) void prep_kernel(
    const int* __restrict__ labels, const float* __restrict__ Amount,
    int* __restrict__ offsets, int* __restrict__ idx_sorted,
    float* __restrict__ w_arr, float* __restrict__ inv_cs,
    float* __restrict__ amount_out, float* __restrict__ out_loss0, int N, int C) {
    __shared__ int hist[1024];
    __shared__ int offs[1025];
    __shared__ int cur[1024];
    const int tid = threadIdx.x;
    for (int c = tid; c < C; c += 1024) { hist[c] = 0; cur[c] = 0; }
    __syncthreads();
    for (int i = tid; i < N; i += 1024) atomicAdd(&hist[labels[i]], 1);
    __syncthreads();
    if (tid == 0) {
        int o = 0;
        for (int c = 0; c < C; ++c) { offs[c] = o; o += hist[c]; }
        offs[C] = o;
    }
    __syncthreads();
    for (int c = tid; c < C; c += 1024) {
        float cf = (float)hist[c];
        float cs = cf > 0.f ? cf : 1.f;
        inv_cs[c] = 1.f / cs;
        float am = Amount[c];
        float dn = cf + am;
        w_arr[c] = dn > 0.f ? cf / dn : 0.f;
        amount_out[c] = am + cf;
        offsets[c] = offs[c];
    }
    if (tid == 0) { offsets[C] = offs[C]; out_loss0[0] = 0.f; }
    for (int i = tid; i < N; i += 1024) {
        int c = labels[i];
        int p = atomicAdd(&cur[c], 1);
        idx_sorted[offs[c] + p] = i;
    }
}

// ---------------- ave: one block per class ----------------
__global__ __launch_bounds__(512) void ave_kernel(
    const float* __restrict__ feats, const float* __restrict__ Ave_in,
    const int* __restrict__ idx_sorted, const int* __restrict__ offsets,
    const float* __restrict__ w_arr, const float* __restrict__ inv_cs,
    float* __restrict__ ave_new, float* __restrict__ ave_out, int A) {
    __shared__ int idxs[512];
    const int c = blockIdx.x;
    const int base = offsets[c];
    const int nc = offsets[c + 1] - base;
    const float w = w_arr[c];
    const float ic = inv_cs[c];
    for (int col = threadIdx.x; col < A; col += blockDim.x) {
        float sum = 0.f;
        for (int i0 = 0; i0 < nc; i0 += 512) {
            int chunk = min(512, nc - i0);
            __syncthreads();
            for (int j = threadIdx.x; j < chunk; j += blockDim.x)
                idxs[j] = idx_sorted[base + i0 + j];
            __syncthreads();
            int j = 0;
            for (; j + 3 < chunk; j += 4) {
                float f0 = feats[(size_t)idxs[j] * A + col];
                float f1 = feats[(size_t)idxs[j + 1] * A + col];
                float f2 = feats[(size_t)idxs[j + 2] * A + col];
                float f3 = feats[(size_t)idxs[j + 3] * A + col];
                sum += f0 + f1 + f2 + f3;
            }
            for (; j < chunk; ++j) sum += feats[(size_t)idxs[j] * A + col];
        }
        float av = sum * ic;
        ave_new[(size_t)c * A + col] = av;
        ave_out[(size_t)c * A + col] = Ave_in[(size_t)c * A + col] * (1.f - w) + av * w;
    }
}

// ---------------- cov (+ balanced loss riders) ----------------
__global__ __launch_bounds__(256) void cov_kernel(
    const float* __restrict__ feats, const float* __restrict__ cov_in,
    const float* __restrict__ ave_new, const float* __restrict__ Ave_in,
    const float* __restrict__ y_s, const int* __restrict__ labels,
    const int* __restrict__ idx_sorted, const int* __restrict__ offsets,
    const float* __restrict__ w_arr, const float* __restrict__ inv_cs,
    float* __restrict__ out_cov, float* __restrict__ out_loss0,
    int N, int C, int A, float invN) {

    // ---- loss rider blocks (z >= C): 16*LZ blocks, 4 waves each ----
    if ((int)blockIdx.z >= C) {
        __shared__ float bsum[4];
        const int lane = threadIdx.x & 63;
        const int wv = threadIdx.x >> 6;
        const int bxy = blockIdx.y * gridDim.x + blockIdx.x;
        const int bid = (blockIdx.z - C) * (gridDim.x * gridDim.y) + bxy;
        const int nwaves = LZ * gridDim.x * gridDim.y * 4;
        const int gw = bid * 4 + wv;
        float wsum = 0.f;
        for (int r = gw; r < N; r += nwaves) {
            const float* row = y_s + (size_t)r * C;
            float m = -1e30f;
            for (int col = lane; col < C; col += 64) m = fmaxf(m, row[col]);
            #pragma unroll
            for (int off = 32; off > 0; off >>= 1) m = fmaxf(m, __shfl_xor(m, off));
            float se = 0.f;
            for (int col = lane; col < C; col += 64) se += __expf(row[col] - m);
            #pragma unroll
            for (int off = 32; off > 0; off >>= 1) se += __shfl_xor(se, off);
            if (lane == 0) wsum += -(row[labels[r]] - m - __logf(se));
        }
        if (lane == 0) bsum[wv] = wsum;
        __syncthreads();
        if (threadIdx.x == 0)
            atomicAdd(out_loss0, (bsum[0] + bsum[1] + bsum[2] + bsum[3]) * invN);
        return;
    }

    // ---- cov tile ----
    const int c  = blockIdx.z;
    const int a0 = blockIdx.y * TM;
    const int b0 = blockIdx.x * TM;
    const int tid = threadIdx.x;

    __shared__ float Xa[KC][LSTR];
    __shared__ float Xb[KC][LSTR];
    __shared__ float aveA[TM], aveB[TM], dA[TM], dB[TM];

    if (tid < TM) {
        float av = ave_new[(size_t)c * A + a0 + tid];
        aveA[tid] = av;
        dA[tid] = Ave_in[(size_t)c * A + a0 + tid] - av;
    } else {
        int t = tid - TM;
        float bv = ave_new[(size_t)c * A + b0 + t];
        aveB[t] = bv;
        dB[t] = Ave_in[(size_t)c * A + b0 + t] - bv;
    }

    const float w   = w_arr[c];
    const float omw = 1.f - w;
    const float s   = inv_cs[c] * w;
    const float aw  = w * omw;
    const size_t cbase = (size_t)c * A * A;
    const int ty = tid >> 4, tx = tid & 15;

    if (s > 0.f) {
        float acc[2][4][2][4] = {};
        if (omw != 0.f) {
            // fold cov_in*(1-w) into acc init (read overlaps k-loop); skipped when w==1
            const float sc = omw / s;
            #pragma unroll
            for (int ri = 0; ri < 2; ++ri)
                #pragma unroll
                for (int i = 0; i < 4; ++i) {
                    const size_t rowo = cbase + (size_t)(a0 + ri * 64 + ty * 4 + i) * A + b0;
                    #pragma unroll
                    for (int ci = 0; ci < 2; ++ci) {
                        float4 co = *reinterpret_cast<const float4*>(&cov_in[rowo + ci * 64 + tx * 4]);
                        acc[ri][i][ci][0] = co.x * sc;
                        acc[ri][i][ci][1] = co.y * sc;
                        acc[ri][i][ci][2] = co.z * sc;
                        acc[ri][i][ci][3] = co.w * sc;
                    }
                }
        }

        const int base = offsets[c];
        const int nc = offsets[c + 1] - base;
        const int cg = tx * 4;        // staging col group

        __syncthreads();              // aveA/aveB ready

        for (int kk = 0; kk < nc; kk += KC) {
            // stage rows ty and ty+16 of this chunk (KC=32), both sides, 8 indep float4 loads
            float4 v[2][4];           // [rowhalf][a0,a1,b0,b1]
            #pragma unroll
            for (int h = 0; h < 2; ++h) {
                const int li = ty + h * 16;
                #pragma unroll
                for (int q = 0; q < 4; ++q)
                    v[h][q] = make_float4(0.f, 0.f, 0.f, 0.f);
                if (kk + li < nc) {
                    int row = idx_sorted[base + kk + li];
                    const float* fr = feats + (size_t)row * A;
                    v[h][0] = *reinterpret_cast<const float4*>(fr + a0 + cg);
                    v[h][1] = *reinterpret_cast<const float4*>(fr + a0 + cg + 64);
                    v[h][2] = *reinterpret_cast<const float4*>(fr + b0 + cg);
                    v[h][3] = *reinterpret_cast<const float4*>(fr + b0 + cg + 64);
                    v[h][0].x -= aveA[cg];      v[h][0].y -= aveA[cg + 1];  v[h][0].z -= aveA[cg + 2];  v[h][0].w -= aveA[cg + 3];
                    v[h][1].x -= aveA[cg + 64]; v[h][1].y -= aveA[cg + 65]; v[h][1].z -= aveA[cg + 66]; v[h][1].w -= aveA[cg + 67];
                    v[h][2].x -= aveB[cg];      v[h][2].y -= aveB[cg + 1];  v[h][2].z -= aveB[cg + 2];  v[h][2].w -= aveB[cg + 3];
                    v[h][3].x -= aveB[cg + 64]; v[h][3].y -= aveB[cg + 65]; v[h][3].z -= aveB[cg + 66]; v[h][3].w -= aveB[cg + 67];
                }
            }
            __syncthreads();          // protect previous chunk's fragment reads
            #pragma unroll
            for (int h = 0; h < 2; ++h) {
                const int li = ty + h * 16;
                *reinterpret_cast<float4*>(&Xa[li][cg])      = v[h][0];
                *reinterpret_cast<float4*>(&Xa[li][cg + 64]) = v[h][1];
                *reinterpret_cast<float4*>(&Xb[li][cg])      = v[h][2];
                *reinterpret_cast<float4*>(&Xb[li][cg + 64]) = v[h][3];
            }
            __syncthreads();

            #pragma unroll
            for (int k = 0; k < KC; ++k) {   // zero-padded tail rows are safe
                float4 a0v = *reinterpret_cast<const float4*>(&Xa[k][ty * 4]);
                float4 a1v = *reinterpret_cast<const float4*>(&Xa[k][64 + ty * 4]);
                float4 b0v = *reinterpret_cast<const float4*>(&Xb[k][tx * 4]);
                float4 b1v = *reinterpret_cast<const float4*>(&Xb[k][64 + tx * 4]);
                float af[2][4] = {{a0v.x, a0v.y, a0v.z, a0v.w}, {a1v.x, a1v.y, a1v.z, a1v.w}};
                float bf[2][4] = {{b0v.x, b0v.y, b0v.z, b0v.w}, {b1v.x, b1v.y, b1v.z, b1v.w}};
                #pragma unroll
                for (int ri = 0; ri < 2; ++ri)
                    #pragma unroll
                    for (int i = 0; i < 4; ++i)
                        #pragma unroll
                        for (int ci = 0; ci < 2; ++ci)
                            #pragma unroll
                            for (int j = 0; j < 4; ++j)
                                acc[ri][i][ci][j] += af[ri][i] * bf[ci][j];
            }
        }

        // epilogue: out = acc*s + w(1-w)*dA*dB ; nontemporal (write-once stream)
        float db[2][4];
        #pragma unroll
        for (int ci = 0; ci < 2; ++ci)
            #pragma unroll
            for (int j = 0; j < 4; ++j) db[ci][j] = dB[ci * 64 + tx * 4 + j];

        #pragma unroll
        for (int ri = 0; ri < 2; ++ri)
            #pragma unroll
            for (int i = 0; i < 4; ++i) {
                float da = aw * dA[ri * 64 + ty * 4 + i];
                const size_t rowo = cbase + (size_t)(a0 + ri * 64 + ty * 4 + i) * A + b0;
                #pragma unroll
                for (int ci = 0; ci < 2; ++ci) {
                    nf4 res;
                    res.x = acc[ri][i][ci][0] * s + da * db[ci][0];
                    res.y = acc[ri][i][ci][1] * s + da * db[ci][1];
                    res.z = acc[ri][i][ci][2] * s + da * db[ci][2];
                    res.w = acc[ri][i][ci][3] * s + da * db[ci][3];
                    __builtin_nontemporal_store(res,
                        reinterpret_cast<nf4*>(&out_cov[rowo + ci * 64 + tx * 4]));
                }
            }
    } else {
        // w == 0: new_cov = cov_in * (1-w)
        for (int t = tid; t < TM * TM / 4; t += 256) {
            const int r = t >> 5;
            const int c4 = (t & 31) * 4;
            const size_t o = cbase + (size_t)(a0 + r) * A + b0 + c4;
            float4 co = *reinterpret_cast<const float4*>(&cov_in[o]);
            nf4 res;
            res.x = co.x * omw; res.y = co.y * omw; res.z = co.z * omw; res.w = co.w * omw;
            __builtin_nontemporal_store(res, reinterpret_cast<nf4*>(&out_cov[o]));
        }
    }
}

extern "C" void kernel_launch(void* const* d_in, const int* in_sizes, int n_in,
                              void* d_out, int out_size, void* d_ws, size_t ws_size,
                              hipStream_t stream) {
    const float* feats  = (const float*)d_in[0];
    const float* y_s    = (const float*)d_in[1];
    const float* cov_in = (const float*)d_in[2];
    const float* Ave_in = (const float*)d_in[3];
    const float* Amount = (const float*)d_in[4];
    const int*   labels = (const int*)d_in[5];

    const int C = in_sizes[4];
    const int N = in_sizes[5];
    const int A = in_sizes[3] / C;

    float* out      = (float*)d_out;
    float* out_loss = out;
    float* out_cov  = out + 1;
    float* out_ave  = out_cov + (size_t)C * A * A;
    float* out_amt  = out_ave + (size_t)C * A;

    char* w8 = (char*)d_ws;
    int* offsets    = (int*)w8;   w8 += (size_t)(C + 1) * sizeof(int);
    int* idx_sorted = (int*)w8;   w8 += (size_t)N * sizeof(int);
    float* w_arr    = (float*)w8; w8 += (size_t)C * sizeof(float);
    float* inv_cs   = (float*)w8; w8 += (size_t)C * sizeof(float);
    float* ave_new  = (float*)w8; w8 += (size_t)C * A * sizeof(float);

    prep_kernel<<<1, 1024, 0, stream>>>(labels, Amount, offsets, idx_sorted,
                                        w_arr, inv_cs, out_amt, out_loss, N, C);
    ave_kernel<<<C, 512, 0, stream>>>(feats, Ave_in, idx_sorted, offsets,
                                      w_arr, inv_cs, ave_new, out_ave, A);
    dim3 grid(A / TM, A / TM, C + LZ);
    cov_kernel<<<grid, 256, 0, stream>>>(feats, cov_in, ave_new, Ave_in, y_s, labels,
                                         idx_sorted, offsets, w_arr, inv_cs,
                                         out_cov, out_loss, N, C, A, 1.f / (float)N);
}

// Round 8
// 221.617 us; speedup vs baseline: 1.0508x; 1.0508x over previous
//
#include <hip/hip_runtime.h>

// N=4096, A=512, C=100 (derived at launch).
// Outputs flat: [loss(1), new_cov(C*A*A), new_ave(C*A), new_amount(C)]
//
// 3 dispatches:
//   prep  : 1 block — histogram, scan, per-class scalars, counting-sort, zero loss.
//   ave   : C blocks — per-class mean + new_ave.
//   cov   : grid (A/TM, A/TM, C+LZ). z<C: 128x128 cov tile, fp32 8x8/thread,
//           software-pipelined staging (next chunk's global loads issued before
//           current chunk's FMA burst), FMA bounded to valid k-rows,
//           nontemporal streaming stores, cov_in read skipped when w==1.
//           z>=C: LZ*16 blocks compute CE loss (balanced, overlaps cov drain).

#define TM 128
#define KC 16      // members per k-chunk
#define LSTR 132   // padded LDS row stride (floats)
#define LZ 16      // extra z-slices for loss blocks

typedef float nf4 __attribute__((ext_vector_type(4)));   // native vector for nontemporal builtins

// ---------------- prep ----------------
__global__ __launch_bounds__(1024) void prep_kernel(
    const int* __restrict__ labels, const float* __restrict__ Amount,
    int* __restrict__ offsets, int* __restrict__ idx_sorted,
    float* __restrict__ w_arr, float* __restrict__ inv_cs,
    float* __restrict__ amount_out, float* __restrict__ out_loss0, int N, int C) {
    __shared__ int hist[1024];
    __shared__ int offs[1025];
    __shared__ int cur[1024];
    const int tid = threadIdx.x;
    for (int c = tid; c < C; c += 1024) { hist[c] = 0; cur[c] = 0; }
    __syncthreads();
    for (int i = tid; i < N; i += 1024) atomicAdd(&hist[labels[i]], 1);
    __syncthreads();
    if (tid == 0) {
        int o = 0;
        for (int c = 0; c < C; ++c) { offs[c] = o; o += hist[c]; }
        offs[C] = o;
    }
    __syncthreads();
    for (int c = tid; c < C; c += 1024) {
        float cf = (float)hist[c];
        float cs = cf > 0.f ? cf : 1.f;
        inv_cs[c] = 1.f / cs;
        float am = Amount[c];
        float dn = cf + am;
        w_arr[c] = dn > 0.f ? cf / dn : 0.f;
        amount_out[c] = am + cf;
        offsets[c] = offs[c];
    }
    if (tid == 0) { offsets[C] = offs[C]; out_loss0[0] = 0.f; }
    for (int i = tid; i < N; i += 1024) {
        int c = labels[i];
        int p = atomicAdd(&cur[c], 1);
        idx_sorted[offs[c] + p] = i;
    }
}

// ---------------- ave: one block per class ----------------
__global__ __launch_bounds__(512) void ave_kernel(
    const float* __restrict__ feats, const float* __restrict__ Ave_in,
    const int* __restrict__ idx_sorted, const int* __restrict__ offsets,
    const float* __restrict__ w_arr, const float* __restrict__ inv_cs,
    float* __restrict__ ave_new, float* __restrict__ ave_out, int A) {
    __shared__ int idxs[512];
    const int c = blockIdx.x;
    const int base = offsets[c];
    const int nc = offsets[c + 1] - base;
    const float w = w_arr[c];
    const float ic = inv_cs[c];
    for (int col = threadIdx.x; col < A; col += blockDim.x) {
        float sum = 0.f;
        for (int i0 = 0; i0 < nc; i0 += 512) {
            int chunk = min(512, nc - i0);
            __syncthreads();
            for (int j = threadIdx.x; j < chunk; j += blockDim.x)
                idxs[j] = idx_sorted[base + i0 + j];
            __syncthreads();
            int j = 0;
            for (; j + 3 < chunk; j += 4) {
                float f0 = feats[(size_t)idxs[j] * A + col];
                float f1 = feats[(size_t)idxs[j + 1] * A + col];
                float f2 = feats[(size_t)idxs[j + 2] * A + col];
                float f3 = feats[(size_t)idxs[j + 3] * A + col];
                sum += f0 + f1 + f2 + f3;
            }
            for (; j < chunk; ++j) sum += feats[(size_t)idxs[j] * A + col];
        }
        float av = sum * ic;
        ave_new[(size_t)c * A + col] = av;
        ave_out[(size_t)c * A + col] = Ave_in[(size_t)c * A + col] * (1.f - w) + av * w;
    }
}

// ---------------- cov (+ balanced loss riders) ----------------
__global__ __launch_bounds__(256) void cov_kernel(
    const float* __restrict__ feats, const float* __restrict__ cov_in,
    const float* __restrict__ ave_new, const float* __restrict__ Ave_in,
    const float* __restrict__ y_s, const int* __restrict__ labels,
    const int* __restrict__ idx_sorted, const int* __restrict__ offsets,
    const float* __restrict__ w_arr, const float* __restrict__ inv_cs,
    float* __restrict__ out_cov, float* __restrict__ out_loss0,
    int N, int C, int A, float invN) {

    // ---- loss rider blocks (z >= C): 16*LZ blocks, 4 waves each ----
    if ((int)blockIdx.z >= C) {
        __shared__ float bsum[4];
        const int lane = threadIdx.x & 63;
        const int wv = threadIdx.x >> 6;
        const int bxy = blockIdx.y * gridDim.x + blockIdx.x;
        const int bid = (blockIdx.z - C) * (gridDim.x * gridDim.y) + bxy;
        const int nwaves = LZ * gridDim.x * gridDim.y * 4;
        const int gw = bid * 4 + wv;
        float wsum = 0.f;
        for (int r = gw; r < N; r += nwaves) {
            const float* row = y_s + (size_t)r * C;
            float m = -1e30f;
            for (int col = lane; col < C; col += 64) m = fmaxf(m, row[col]);
            #pragma unroll
            for (int off = 32; off > 0; off >>= 1) m = fmaxf(m, __shfl_xor(m, off));
            float se = 0.f;
            for (int col = lane; col < C; col += 64) se += __expf(row[col] - m);
            #pragma unroll
            for (int off = 32; off > 0; off >>= 1) se += __shfl_xor(se, off);
            if (lane == 0) wsum += -(row[labels[r]] - m - __logf(se));
        }
        if (lane == 0) bsum[wv] = wsum;
        __syncthreads();
        if (threadIdx.x == 0)
            atomicAdd(out_loss0, (bsum[0] + bsum[1] + bsum[2] + bsum[3]) * invN);
        return;
    }

    // ---- cov tile ----
    const int c  = blockIdx.z;
    const int a0 = blockIdx.y * TM;
    const int b0 = blockIdx.x * TM;
    const int tid = threadIdx.x;

    __shared__ float Xa[KC][LSTR];
    __shared__ float Xb[KC][LSTR];
    __shared__ float aveA[TM], aveB[TM], dA[TM], dB[TM];

    if (tid < TM) {
        float av = ave_new[(size_t)c * A + a0 + tid];
        aveA[tid] = av;
        dA[tid] = Ave_in[(size_t)c * A + a0 + tid] - av;
    } else {
        int t = tid - TM;
        float bv = ave_new[(size_t)c * A + b0 + t];
        aveB[t] = bv;
        dB[t] = Ave_in[(size_t)c * A + b0 + t] - bv;
    }

    const float w   = w_arr[c];
    const float omw = 1.f - w;
    const float s   = inv_cs[c] * w;
    const float aw  = w * omw;
    const size_t cbase = (size_t)c * A * A;
    const int ty = tid >> 4, tx = tid & 15;

    if (s > 0.f) {
        const int base = offsets[c];
        const int nc = offsets[c + 1] - base;
        const int li = ty;            // staging member row (0..15)
        const int cg = tx * 4;        // staging col group
        const int nchunks = (nc + KC - 1) / KC;

        __syncthreads();              // aveA/aveB ready (needed by staging subtract)

        float4 v0, v1, v2, v3;        // pipeline registers for next chunk
        // --- prologue: load chunk 0 ---
        {
            v0 = make_float4(0.f, 0.f, 0.f, 0.f); v1 = v0; v2 = v0; v3 = v0;
            if (li < nc) {
                int row = idx_sorted[base + li];
                const float* fr = feats + (size_t)row * A;
                v0 = *reinterpret_cast<const float4*>(fr + a0 + cg);
                v1 = *reinterpret_cast<const float4*>(fr + a0 + cg + 64);
                v2 = *reinterpret_cast<const float4*>(fr + b0 + cg);
                v3 = *reinterpret_cast<const float4*>(fr + b0 + cg + 64);
                v0.x -= aveA[cg];      v0.y -= aveA[cg + 1];  v0.z -= aveA[cg + 2];  v0.w -= aveA[cg + 3];
                v1.x -= aveA[cg + 64]; v1.y -= aveA[cg + 65]; v1.z -= aveA[cg + 66]; v1.w -= aveA[cg + 67];
                v2.x -= aveB[cg];      v2.y -= aveB[cg + 1];  v2.z -= aveB[cg + 2];  v2.w -= aveB[cg + 3];
                v3.x -= aveB[cg + 64]; v3.y -= aveB[cg + 65]; v3.z -= aveB[cg + 66]; v3.w -= aveB[cg + 67];
            }
        }

        float acc[2][4][2][4] = {};
        if (omw != 0.f) {
            // fold cov_in*(1-w) into acc init (read overlaps k-loop); skipped when w==1
            const float sc = omw / s;
            #pragma unroll
            for (int ri = 0; ri < 2; ++ri)
                #pragma unroll
                for (int i = 0; i < 4; ++i) {
                    const size_t rowo = cbase + (size_t)(a0 + ri * 64 + ty * 4 + i) * A + b0;
                    #pragma unroll
                    for (int ci = 0; ci < 2; ++ci) {
                        float4 co = *reinterpret_cast<const float4*>(&cov_in[rowo + ci * 64 + tx * 4]);
                        acc[ri][i][ci][0] = co.x * sc;
                        acc[ri][i][ci][1] = co.y * sc;
                        acc[ri][i][ci][2] = co.z * sc;
                        acc[ri][i][ci][3] = co.w * sc;
                    }
                }
        }

        for (int ch = 0; ch < nchunks; ++ch) {
            __syncthreads();          // previous chunk's FMA reads complete
            *reinterpret_cast<float4*>(&Xa[li][cg])      = v0;
            *reinterpret_cast<float4*>(&Xa[li][cg + 64]) = v1;
            *reinterpret_cast<float4*>(&Xb[li][cg])      = v2;
            *reinterpret_cast<float4*>(&Xb[li][cg + 64]) = v3;
            __syncthreads();          // LDS ready for FMA

            // --- issue next chunk's global loads NOW (fly during the FMA burst) ---
            if (ch + 1 < nchunks) {
                const int kk = (ch + 1) * KC;
                v0 = make_float4(0.f, 0.f, 0.f, 0.f); v1 = v0; v2 = v0; v3 = v0;
                if (kk + li < nc) {
                    int row = idx_sorted[base + kk + li];
                    const float* fr = feats + (size_t)row * A;
                    v0 = *reinterpret_cast<const float4*>(fr + a0 + cg);
                    v1 = *reinterpret_cast<const float4*>(fr + a0 + cg + 64);
                    v2 = *reinterpret_cast<const float4*>(fr + b0 + cg);
                    v3 = *reinterpret_cast<const float4*>(fr + b0 + cg + 64);
                    v0.x -= aveA[cg];      v0.y -= aveA[cg + 1];  v0.z -= aveA[cg + 2];  v0.w -= aveA[cg + 3];
                    v1.x -= aveA[cg + 64]; v1.y -= aveA[cg + 65]; v1.z -= aveA[cg + 66]; v1.w -= aveA[cg + 67];
                    v2.x -= aveB[cg];      v2.y -= aveB[cg + 1];  v2.z -= aveB[cg + 2];  v2.w -= aveB[cg + 3];
                    v3.x -= aveB[cg + 64]; v3.y -= aveB[cg + 65]; v3.z -= aveB[cg + 66]; v3.w -= aveB[cg + 67];
                }
            }

            const int kn = min(KC, nc - ch * KC);   // skip zero-padded tail rows
            if (kn == KC) {
                #pragma unroll
                for (int k = 0; k < KC; ++k) {
                    float4 a0v = *reinterpret_cast<const float4*>(&Xa[k][ty * 4]);
                    float4 a1v = *reinterpret_cast<const float4*>(&Xa[k][64 + ty * 4]);
                    float4 b0v = *reinterpret_cast<const float4*>(&Xb[k][tx * 4]);
                    float4 b1v = *reinterpret_cast<const float4*>(&Xb[k][64 + tx * 4]);
                    float af[2][4] = {{a0v.x, a0v.y, a0v.z, a0v.w}, {a1v.x, a1v.y, a1v.z, a1v.w}};
                    float bf[2][4] = {{b0v.x, b0v.y, b0v.z, b0v.w}, {b1v.x, b1v.y, b1v.z, b1v.w}};
                    #pragma unroll
                    for (int ri = 0; ri < 2; ++ri)
                        #pragma unroll
                        for (int i = 0; i < 4; ++i)
                            #pragma unroll
                            for (int ci = 0; ci < 2; ++ci)
                                #pragma unroll
                                for (int j = 0; j < 4; ++j)
                                    acc[ri][i][ci][j] += af[ri][i] * bf[ci][j];
                }
            } else {
                for (int k = 0; k < kn; ++k) {
                    float4 a0v = *reinterpret_cast<const float4*>(&Xa[k][ty * 4]);
                    float4 a1v = *reinterpret_cast<const float4*>(&Xa[k][64 + ty * 4]);
                    float4 b0v = *reinterpret_cast<const float4*>(&Xb[k][tx * 4]);
                    float4 b1v = *reinterpret_cast<const float4*>(&Xb[k][64 + tx * 4]);
                    float af[2][4] = {{a0v.x, a0v.y, a0v.z, a0v.w}, {a1v.x, a1v.y, a1v.z, a1v.w}};
                    float bf[2][4] = {{b0v.x, b0v.y, b0v.z, b0v.w}, {b1v.x, b1v.y, b1v.z, b1v.w}};
                    #pragma unroll
                    for (int ri = 0; ri < 2; ++ri)
                        #pragma unroll
                        for (int i = 0; i < 4; ++i)
                            #pragma unroll
                            for (int ci = 0; ci < 2; ++ci)
                                #pragma unroll
                                for (int j = 0; j < 4; ++j)
                                    acc[ri][i][ci][j] += af[ri][i] * bf[ci][j];
                }
            }
        }

        // epilogue: out = acc*s + w(1-w)*dA*dB ; nontemporal (write-once stream)
        float db[2][4];
        #pragma unroll
        for (int ci = 0; ci < 2; ++ci)
            #pragma unroll
            for (int j = 0; j < 4; ++j) db[ci][j] = dB[ci * 64 + tx * 4 + j];

        #pragma unroll
        for (int ri = 0; ri < 2; ++ri)
            #pragma unroll
            for (int i = 0; i < 4; ++i) {
                float da = aw * dA[ri * 64 + ty * 4 + i];
                const size_t rowo = cbase + (size_t)(a0 + ri * 64 + ty * 4 + i) * A + b0;
                #pragma unroll
                for (int ci = 0; ci < 2; ++ci) {
                    nf4 res;
                    res.x = acc[ri][i][ci][0] * s + da * db[ci][0];
                    res.y = acc[ri][i][ci][1] * s + da * db[ci][1];
                    res.z = acc[ri][i][ci][2] * s + da * db[ci][2];
                    res.w = acc[ri][i][ci][3] * s + da * db[ci][3];
                    __builtin_nontemporal_store(res,
                        reinterpret_cast<nf4*>(&out_cov[rowo + ci * 64 + tx * 4]));
                }
            }
    } else {
        // w == 0: new_cov = cov_in * (1-w)
        for (int t = tid; t < TM * TM / 4; t += 256) {
            const int r = t >> 5;
            const int c4 = (t & 31) * 4;
            const size_t o = cbase + (size_t)(a0 + r) * A + b0 + c4;
            float4 co = *reinterpret_cast<const float4*>(&cov_in[o]);
            nf4 res;
            res.x = co.x * omw; res.y = co.y * omw; res.z = co.z * omw; res.w = co.w * omw;
            __builtin_nontemporal_store(res, reinterpret_cast<nf4*>(&out_cov[o]));
        }
    }
}

extern "C" void kernel_launch(void* const* d_in, const int* in_sizes, int n_in,
                              void* d_out, int out_size, void* d_ws, size_t ws_size,
                              hipStream_t stream) {
    const float* feats  = (const float*)d_in[0];
    const float* y_s    = (const float*)d_in[1];
    const float* cov_in = (const float*)d_in[2];
    const float* Ave_in = (const float*)d_in[3];
    const float* Amount = (const float*)d_in[4];
    const int*   labels = (const int*)d_in[5];

    const int C = in_sizes[4];
    const int N = in_sizes[5];
    const int A = in_sizes[3] / C;

    float* out      = (float*)d_out;
    float* out_loss = out;
    float* out_cov  = out + 1;
    float* out_ave  = out_cov + (size_t)C * A * A;
    float* out_amt  = out_ave + (size_t)C * A;

    char* w8 = (char*)d_ws;
    int* offsets    = (int*)w8;   w8 += (size_t)(C + 1) * sizeof(int);
    int* idx_sorted = (int*)w8;   w8 += (size_t)N * sizeof(int);
    float* w_arr    = (float*)w8; w8 += (size_t)C * sizeof(float);
    float* inv_cs   = (float*)w8; w8 += (size_t)C * sizeof(float);
    float* ave_new  = (float*)w8; w8 += (size_t)C * A * sizeof(float);

    prep_kernel<<<1, 1024, 0, stream>>>(labels, Amount, offsets, idx_sorted,
                                        w_arr, inv_cs, out_amt, out_loss, N, C);
    ave_kernel<<<C, 512, 0, stream>>>(feats, Ave_in, idx_sorted, offsets,
                                      w_arr, inv_cs, ave_new, out_ave, A);
    dim3 grid(A / TM, A / TM, C + LZ);
    cov_kernel<<<grid, 256, 0, stream>>>(feats, cov_in, ave_new, Ave_in, y_s, labels,
                                         idx_sorted, offsets, w_arr, inv_cs,
                                         out_cov, out_loss, N, C, A, 1.f / (float)N);
}